// Round 1
// baseline (484.338 us; speedup 1.0000x reference)
//
#include <hip/hip_runtime.h>
#include <hip/hip_bf16.h>

using bf16 = __hip_bfloat16;
typedef __attribute__((ext_vector_type(8))) short short8;
typedef __attribute__((ext_vector_type(4))) float f32x4;

#define NLAY 2
#define NN1 8
#define NN2 8
#define PP 1024
#define DD 768
#define MROWS (NN1*PP)   // 8192
#define BM 128
#define BN 128
#define BK 64
#define NTILE (MROWS/BN) // 64 col tiles

// ---------------- normalize rows + convert to bf16 -------------------------
// one wave per row of 768 floats; 4 rows per 256-thread block
__global__ __launch_bounds__(256) void normalize_kernel(
    const float* __restrict__ in, bf16* __restrict__ out, int nrows) {
  int row  = blockIdx.x * 4 + (threadIdx.x >> 6);
  int lane = threadIdx.x & 63;
  if (row >= nrows) return;
  const float* src = in + (size_t)row * DD;
  float4 v[3];
  float ss = 0.f;
#pragma unroll
  for (int i = 0; i < 3; i++) {
    v[i] = *reinterpret_cast<const float4*>(src + lane * 4 + i * 256);
    ss += v[i].x * v[i].x + v[i].y * v[i].y + v[i].z * v[i].z + v[i].w * v[i].w;
  }
#pragma unroll
  for (int off = 1; off < 64; off <<= 1) ss += __shfl_xor(ss, off);
  float rn = rsqrtf(ss);
  bf16* dst = out + (size_t)row * DD;
#pragma unroll
  for (int i = 0; i < 3; i++) {
    bf16 tmp[4];
    tmp[0] = __float2bfloat16(v[i].x * rn);
    tmp[1] = __float2bfloat16(v[i].y * rn);
    tmp[2] = __float2bfloat16(v[i].z * rn);
    tmp[3] = __float2bfloat16(v[i].w * rn);
    *reinterpret_cast<uint2*>(dst + lane * 4 + i * 256) =
        *reinterpret_cast<const uint2*>(tmp);
  }
}

// ---------------- GEMM C = A*B^T with fused per-row tile-max ---------------
// grid (NTILE, NTILE, NLAY), 256 threads (4 waves, 2x2), 128x128 tile, BK=64
__global__ __launch_bounds__(256) void gemm_max_kernel(
    const bf16* __restrict__ A, const bf16* __restrict__ Bm,
    float* __restrict__ partials) {
  __shared__ bf16 As[BM * BK];
  __shared__ bf16 Bs[BN * BK];
  __shared__ float red[2][BM];

  const int l     = blockIdx.z;
  const int tilec = blockIdx.x;
  const int tiler = blockIdx.y;
  const bf16* Ab = A  + ((size_t)l * MROWS + (size_t)tiler * BM) * DD;
  const bf16* Bb = Bm + ((size_t)l * MROWS + (size_t)tilec * BN) * DD;

  const int t    = threadIdx.x;
  const int lane = t & 63;
  const int wave = t >> 6;
  const int wm   = wave >> 1;   // 0..1
  const int wn   = wave & 1;    // 0..1

  f32x4 acc[4][4];
#pragma unroll
  for (int m = 0; m < 4; m++)
#pragma unroll
    for (int n = 0; n < 4; n++) acc[m][n] = (f32x4){0.f, 0.f, 0.f, 0.f};

  const int rrow = lane & 15;
  const int krow = lane >> 4;

  for (int kt = 0; kt < DD / BK; kt++) {
    // stage 16KB A tile + 16KB B tile, 16B per thread per call
#pragma unroll
    for (int i = 0; i < 4; i++) {
      int e = i * 256 + t;          // 16-byte unit index within tile
      int r = e >> 3;               // tile row (64 bf16 = 8x16B per row)
      int c = (e & 7) * 8;          // bf16 col within row
      __builtin_amdgcn_global_load_lds(
          (const __attribute__((address_space(1))) void*)(Ab + (size_t)r * DD + kt * BK + c),
          (__attribute__((address_space(3))) void*)(As + e * 8), 16, 0, 0);
    }
#pragma unroll
    for (int i = 0; i < 4; i++) {
      int e = i * 256 + t;
      int r = e >> 3;
      int c = (e & 7) * 8;
      __builtin_amdgcn_global_load_lds(
          (const __attribute__((address_space(1))) void*)(Bb + (size_t)r * DD + kt * BK + c),
          (__attribute__((address_space(3))) void*)(Bs + e * 8), 16, 0, 0);
    }
    __syncthreads();

#pragma unroll
    for (int kk = 0; kk < 2; kk++) {
      const int kcol = kk * 32 + krow * 8;
      short8 a[4], b[4];
#pragma unroll
      for (int m = 0; m < 4; m++) {
        int row = wm * 64 + m * 16 + rrow;
        a[m] = *reinterpret_cast<const short8*>(&As[row * BK + kcol]);
      }
#pragma unroll
      for (int n = 0; n < 4; n++) {
        int row = wn * 64 + n * 16 + rrow;
        b[n] = *reinterpret_cast<const short8*>(&Bs[row * BK + kcol]);
      }
#pragma unroll
      for (int m = 0; m < 4; m++)
#pragma unroll
        for (int n = 0; n < 4; n++)
          acc[m][n] = __builtin_amdgcn_mfma_f32_16x16x32_bf16(a[m], b[n], acc[m][n], 0, 0, 0);
    }
    __syncthreads();
  }

  // epilogue: per-row max over this block's 128 columns
  // C/D layout: col = lane&15, row = (lane>>4)*4 + j
#pragma unroll
  for (int m = 0; m < 4; m++) {
#pragma unroll
    for (int j = 0; j < 4; j++) {
      float v = acc[m][0][j];
      v = fmaxf(v, acc[m][1][j]);
      v = fmaxf(v, acc[m][2][j]);
      v = fmaxf(v, acc[m][3][j]);
#pragma unroll
      for (int off = 1; off < 16; off <<= 1) v = fmaxf(v, __shfl_xor(v, off));
      if (rrow == 0) red[wn][wm * 64 + m * 16 + krow * 4 + j] = v;
    }
  }
  __syncthreads();
  if (t < BM) {
    float v = fmaxf(red[0][t], red[1][t]);
    partials[(((size_t)l * MROWS) + (size_t)tiler * BM + t) * NTILE + tilec] = v;
  }
}

// ---------------- reduce: maxdot -> sp -> scores + spatch ------------------
// one block per n1 (8 blocks), 1024 threads (one per patch p)
__global__ __launch_bounds__(1024) void reduce_kernel(
    const float* __restrict__ partials, const float* __restrict__ mask,
    float* __restrict__ scores, float* __restrict__ spatch) {
  const int n1 = blockIdx.x;
  const int p  = threadIdx.x;
  const int row = n1 * PP + p;
  const float mk = mask[row];

  float sp[16];
  float ssum = 0.f;
#pragma unroll
  for (int l = 0; l < NLAY; l++) {
    const float* pr = partials + ((size_t)l * MROWS + row) * NTILE;
#pragma unroll
    for (int n2 = 0; n2 < NN2; n2++) {
      float md = pr[n2 * 8];
#pragma unroll
      for (int tt = 1; tt < 8; tt++) md = fmaxf(md, pr[n2 * 8 + tt]);
      float d2 = fmaxf(2.f - 2.f * md, 1e-12f);
      float s  = 0.5f * sqrtf(d2) * mk;
      sp[l * 8 + n2] = s;
      ssum += s;
    }
  }
  spatch[row] = ssum * (1.f / 16.f);

  __shared__ float wred[16][16];
  __shared__ float sres[16];
  const int lane = p & 63;
  const int wave = p >> 6;
#pragma unroll
  for (int v = 0; v < 16; v++) {
    float x = sp[v];
#pragma unroll
    for (int off = 1; off < 64; off <<= 1) x = fmaxf(x, __shfl_xor(x, off));
    if (lane == 0) wred[wave][v] = x;
  }
  __syncthreads();
  if (p < 16) {
    float x = wred[0][p];
#pragma unroll
    for (int w = 1; w < 16; w++) x = fmaxf(x, wred[w][p]);
    sres[p] = x;
  }
  __syncthreads();
  if (p == 0) {
    float s = 0.f;
#pragma unroll
    for (int v = 0; v < 16; v++) s += sres[v];
    scores[n1] = s * (1.f / 16.f);
  }
}

// ---------------- bilinear 16x upsample [8,32,32] -> [8,512,512] -----------
__global__ __launch_bounds__(256) void upsample_kernel(
    const float* __restrict__ spatch, float* __restrict__ out) {
  int idx = blockIdx.x * 256 + threadIdx.x;
  if (idx >= NN1 * 512 * 512) return;
  int x = idx & 511;
  int y = (idx >> 9) & 511;
  int n = idx >> 18;
  float sx = (x + 0.5f) * 0.0625f - 0.5f;
  float sy = (y + 0.5f) * 0.0625f - 0.5f;
  int x0 = (int)floorf(sx); float wx = sx - (float)x0;
  int y0 = (int)floorf(sy); float wy = sy - (float)y0;
  int x1 = min(x0 + 1, 31); x0 = max(x0, 0);
  int y1 = min(y0 + 1, 31); y0 = max(y0, 0);
  const float* s = spatch + n * PP;
  float v00 = s[y0 * 32 + x0], v01 = s[y0 * 32 + x1];
  float v10 = s[y1 * 32 + x0], v11 = s[y1 * 32 + x1];
  float v = (1.f - wy) * ((1.f - wx) * v00 + wx * v01) +
            wy * ((1.f - wx) * v10 + wx * v11);
  out[idx] = v;
}

extern "C" void kernel_launch(void* const* d_in, const int* in_sizes, int n_in,
                              void* d_out, int out_size, void* d_ws, size_t ws_size,
                              hipStream_t stream) {
  const float* feats  = (const float*)d_in[0];
  const float* nfeats = (const float*)d_in[1];
  const float* mask   = (const float*)d_in[2];
  float* out = (float*)d_out;

  bf16* Abf = (bf16*)d_ws;                                   // 2*8192*768 bf16
  bf16* Bbf = Abf + (size_t)NLAY * MROWS * DD;               // same size
  float* partials = (float*)(Bbf + (size_t)NLAY * MROWS * DD); // [2][8192][64] f32
  float* spatch   = partials + (size_t)NLAY * MROWS * NTILE;   // [8][1024] f32

  normalize_kernel<<<(NLAY * MROWS) / 4, 256, 0, stream>>>(feats,  Abf, NLAY * MROWS);
  normalize_kernel<<<(NLAY * MROWS) / 4, 256, 0, stream>>>(nfeats, Bbf, NLAY * MROWS);

  dim3 g(NTILE, NTILE, NLAY);
  gemm_max_kernel<<<g, 256, 0, stream>>>(Abf, Bbf, partials);

  reduce_kernel<<<NN1, 1024, 0, stream>>>(partials, mask, out, spatch);

  upsample_kernel<<<(NN1 * 512 * 512) / 256, 256, 0, stream>>>(spatch, out + 8);
}

// Round 2
// 392.772 us; speedup vs baseline: 1.2331x; 1.2331x over previous
//
#include <hip/hip_runtime.h>
#include <hip/hip_bf16.h>

using bf16 = __hip_bfloat16;
typedef __attribute__((ext_vector_type(8))) short short8;
typedef __attribute__((ext_vector_type(4))) float f32x4;

#define NLAY 2
#define NN1 8
#define NN2 8
#define PP 1024
#define DD 768
#define MROWS (NN1*PP)   // 8192
#define BM 256
#define BN 256
#define BK 64
#define NKT (DD/BK)      // 12 K-tiles
#define NCT (MROWS/BN)   // 32 col tiles

// ---------------- normalize rows + convert to bf16 -------------------------
__global__ __launch_bounds__(256) void normalize_kernel(
    const float* __restrict__ in, bf16* __restrict__ out, int nrows) {
  int row  = blockIdx.x * 4 + (threadIdx.x >> 6);
  int lane = threadIdx.x & 63;
  if (row >= nrows) return;
  const float* src = in + (size_t)row * DD;
  float4 v[3];
  float ss = 0.f;
#pragma unroll
  for (int i = 0; i < 3; i++) {
    v[i] = *reinterpret_cast<const float4*>(src + lane * 4 + i * 256);
    ss += v[i].x * v[i].x + v[i].y * v[i].y + v[i].z * v[i].z + v[i].w * v[i].w;
  }
#pragma unroll
  for (int off = 1; off < 64; off <<= 1) ss += __shfl_xor(ss, off);
  float rn = rsqrtf(ss);
  bf16* dst = out + (size_t)row * DD;
#pragma unroll
  for (int i = 0; i < 3; i++) {
    bf16 tmp[4];
    tmp[0] = __float2bfloat16(v[i].x * rn);
    tmp[1] = __float2bfloat16(v[i].y * rn);
    tmp[2] = __float2bfloat16(v[i].z * rn);
    tmp[3] = __float2bfloat16(v[i].w * rn);
    *reinterpret_cast<uint2*>(dst + lane * 4 + i * 256) =
        *reinterpret_cast<const uint2*>(tmp);
  }
}

// ---------------- 256x256 8-phase GEMM with fused per-row tile-max ---------
// 512 threads = 8 waves (2 row x 4 col). LDS: 2 dbuf x 2 half x [128][64] bf16
// for A and B = 128 KiB. Swizzle: logical 16B slot s at row r stored at
// s^(r&7); global source pre-swizzled, ds_read applies same XOR.

__device__ __forceinline__ short8 ld_frag(const bf16* h, int r, int kc8) {
  return *reinterpret_cast<const short8*>(h + r * 64 + (((kc8) ^ (r & 7)) << 3));
}

// stage one 128x64 half-tile: 2 x global_load_lds per thread, linear LDS dest,
// inverse-swizzled global source column
#define STAGE(Gbase, Lds) do {                                                  \
  _Pragma("unroll")                                                             \
  for (int i_ = 0; i_ < 2; i_++) {                                              \
    int u_ = i_ * 512 + t;                                                      \
    int r_ = u_ >> 3, s_ = u_ & 7;                                              \
    int sc_ = ((s_ ^ (r_ & 7)) << 3);                                           \
    __builtin_amdgcn_global_load_lds(                                           \
      (const __attribute__((address_space(1))) void*)((Gbase) + (size_t)r_ * DD + sc_), \
      (__attribute__((address_space(3))) void*)((Lds) + u_ * 8), 16, 0, 0);     \
  } } while (0)

#define VM4 asm volatile("s_waitcnt vmcnt(4)" ::: "memory")

#define PHASE(buf, qm, qn, STG, VMC) do {                                       \
  short8 af_[4][2], bf_[2][2];                                                  \
  _Pragma("unroll")                                                             \
  for (int m_ = 0; m_ < 4; m_++)                                                \
    _Pragma("unroll")                                                           \
    for (int ks_ = 0; ks_ < 2; ks_++)                                           \
      af_[m_][ks_] = ld_frag(&As[buf][qm][0], wr * 64 + m_ * 16 + rrow, ks_ * 4 + krow); \
  _Pragma("unroll")                                                             \
  for (int n_ = 0; n_ < 2; n_++)                                                \
    _Pragma("unroll")                                                           \
    for (int ks_ = 0; ks_ < 2; ks_++)                                           \
      bf_[n_][ks_] = ld_frag(&Bs[buf][qn][0], wc * 32 + n_ * 16 + rrow, ks_ * 4 + krow); \
  STG;                                                                          \
  __builtin_amdgcn_s_barrier();                                                 \
  asm volatile("s_waitcnt lgkmcnt(0)" ::: "memory");                            \
  __builtin_amdgcn_s_setprio(1);                                                \
  _Pragma("unroll")                                                             \
  for (int m_ = 0; m_ < 4; m_++)                                                \
    _Pragma("unroll")                                                           \
    for (int n_ = 0; n_ < 2; n_++)                                              \
      _Pragma("unroll")                                                         \
      for (int ks_ = 0; ks_ < 2; ks_++)                                         \
        acc[(qm) * 4 + m_][(qn) * 2 + n_] = __builtin_amdgcn_mfma_f32_16x16x32_bf16( \
            af_[m_][ks_], bf_[n_][ks_], acc[(qm) * 4 + m_][(qn) * 2 + n_], 0, 0, 0); \
  __builtin_amdgcn_s_setprio(0);                                                \
  VMC;                                                                          \
  __builtin_amdgcn_s_barrier();                                                 \
} while (0)

__global__ __launch_bounds__(512, 2) void gemm_max_kernel(
    const bf16* __restrict__ A, const bf16* __restrict__ Bm,
    float* __restrict__ partials) {
  __shared__ bf16 As[2][2][128 * 64];
  __shared__ bf16 Bs[2][2][128 * 64];
  __shared__ float red[4][256];

  const int l     = blockIdx.z;
  const int tilec = blockIdx.x;
  const int tiler = blockIdx.y;
  const bf16* Ab = A  + ((size_t)l * MROWS + (size_t)tiler * BM) * DD;
  const bf16* Bb = Bm + ((size_t)l * MROWS + (size_t)tilec * BN) * DD;

  const int t    = threadIdx.x;
  const int lane = t & 63;
  const int wave = t >> 6;
  const int wr   = wave >> 2;   // 0..1
  const int wc   = wave & 3;    // 0..3
  const int rrow = lane & 15;
  const int krow = lane >> 4;

  f32x4 acc[8][4];
#pragma unroll
  for (int m = 0; m < 8; m++)
#pragma unroll
    for (int n = 0; n < 4; n++) acc[m][n] = (f32x4){0.f, 0.f, 0.f, 0.f};

  // prologue: tile0 -> buf0 (all 4 halves), tile1 -> buf1 (A0,B0)
  STAGE(Ab,                         &As[0][0][0]);
  STAGE(Bb,                         &Bs[0][0][0]);
  STAGE(Ab + (size_t)128 * DD,      &As[0][1][0]);
  STAGE(Bb + (size_t)128 * DD,      &Bs[0][1][0]);
  STAGE(Ab + BK,                    &As[1][0][0]);
  STAGE(Bb + BK,                    &Bs[1][0][0]);
  VM4;
  __builtin_amdgcn_s_barrier();

  for (int i = 0; i < NKT / 2; i++) {
    const int ktP = 2 * i + 1;   // finish staging odd tile -> buf1 (A1,B1)
    const int ktE = 2 * i + 2;   // next even tile -> buf0 (all 4)
    const int ktO = 2 * i + 3;   // next odd tile -> buf1 (A0,B0)
    // phases 1-4: compute buf0
    PHASE(0, 0, 0, STAGE(Ab + (size_t)128 * DD + (size_t)ktP * BK, &As[1][1][0]), (void)0);
    PHASE(0, 0, 1, STAGE(Bb + (size_t)128 * DD + (size_t)ktP * BK, &Bs[1][1][0]), (void)0);
    PHASE(0, 1, 0, if (ktE < NKT) STAGE(Ab + (size_t)ktE * BK, &As[0][0][0]), (void)0);
    PHASE(0, 1, 1, if (ktE < NKT) STAGE(Bb + (size_t)ktE * BK, &Bs[0][0][0]), VM4);
    // phases 5-8: compute buf1
    PHASE(1, 0, 0, if (ktE < NKT) STAGE(Ab + (size_t)128 * DD + (size_t)ktE * BK, &As[0][1][0]), (void)0);
    PHASE(1, 0, 1, if (ktE < NKT) STAGE(Bb + (size_t)128 * DD + (size_t)ktE * BK, &Bs[0][1][0]), (void)0);
    PHASE(1, 1, 0, if (ktO < NKT) STAGE(Ab + (size_t)ktO * BK, &As[1][0][0]), (void)0);
    PHASE(1, 1, 1, if (ktO < NKT) STAGE(Bb + (size_t)ktO * BK, &Bs[1][0][0]), VM4);
  }

  // epilogue: per-row max over this block's 256 columns.
  // C/D frag: col = rrow (lane&15), row = krow*4 + j
#pragma unroll
  for (int m = 0; m < 8; m++) {
#pragma unroll
    for (int j = 0; j < 4; j++) {
      float v = acc[m][0][j];
      v = fmaxf(v, acc[m][1][j]);
      v = fmaxf(v, acc[m][2][j]);
      v = fmaxf(v, acc[m][3][j]);
#pragma unroll
      for (int off = 1; off < 16; off <<= 1) v = fmaxf(v, __shfl_xor(v, off));
      if (rrow == 0) {
        int row = (m >> 2) * 128 + wr * 64 + (m & 3) * 16 + krow * 4 + j;
        red[wc][row] = v;
      }
    }
  }
  __syncthreads();
  if (t < 256) {
    float v = fmaxf(fmaxf(red[0][t], red[1][t]), fmaxf(red[2][t], red[3][t]));
    partials[((size_t)l * MROWS + (size_t)tiler * BM + t) * NCT + tilec] = v;
  }
}

// ---------------- reduce: maxdot -> sp -> scores + spatch ------------------
__global__ __launch_bounds__(1024) void reduce_kernel(
    const float* __restrict__ partials, const float* __restrict__ mask,
    float* __restrict__ scores, float* __restrict__ spatch) {
  const int n1 = blockIdx.x;
  const int p  = threadIdx.x;
  const int row = n1 * PP + p;
  const float mk = mask[row];

  float sp[16];
  float ssum = 0.f;
#pragma unroll
  for (int l = 0; l < NLAY; l++) {
    const float* pr = partials + ((size_t)l * MROWS + row) * NCT;
#pragma unroll
    for (int n2 = 0; n2 < NN2; n2++) {
      float md = pr[n2 * 4];
#pragma unroll
      for (int tt = 1; tt < 4; tt++) md = fmaxf(md, pr[n2 * 4 + tt]);
      float d2 = fmaxf(2.f - 2.f * md, 1e-12f);
      float s  = 0.5f * sqrtf(d2) * mk;
      sp[l * 8 + n2] = s;
      ssum += s;
    }
  }
  spatch[row] = ssum * (1.f / 16.f);

  __shared__ float wred[16][16];
  __shared__ float sres[16];
  const int lane = p & 63;
  const int wave = p >> 6;
#pragma unroll
  for (int v = 0; v < 16; v++) {
    float x = sp[v];
#pragma unroll
    for (int off = 1; off < 64; off <<= 1) x = fmaxf(x, __shfl_xor(x, off));
    if (lane == 0) wred[wave][v] = x;
  }
  __syncthreads();
  if (p < 16) {
    float x = wred[0][p];
#pragma unroll
    for (int w = 1; w < 16; w++) x = fmaxf(x, wred[w][p]);
    sres[p] = x;
  }
  __syncthreads();
  if (p == 0) {
    float s = 0.f;
#pragma unroll
    for (int v = 0; v < 16; v++) s += sres[v];
    scores[n1] = s * (1.f / 16.f);
  }
}

// ---------------- bilinear 16x upsample [8,32,32] -> [8,512,512] -----------
__global__ __launch_bounds__(256) void upsample_kernel(
    const float* __restrict__ spatch, float* __restrict__ out) {
  int idx = blockIdx.x * 256 + threadIdx.x;
  if (idx >= NN1 * 512 * 512) return;
  int x = idx & 511;
  int y = (idx >> 9) & 511;
  int n = idx >> 18;
  float sx = (x + 0.5f) * 0.0625f - 0.5f;
  float sy = (y + 0.5f) * 0.0625f - 0.5f;
  int x0 = (int)floorf(sx); float wx = sx - (float)x0;
  int y0 = (int)floorf(sy); float wy = sy - (float)y0;
  int x1 = min(x0 + 1, 31); x0 = max(x0, 0);
  int y1 = min(y0 + 1, 31); y0 = max(y0, 0);
  const float* s = spatch + n * PP;
  float v00 = s[y0 * 32 + x0], v01 = s[y0 * 32 + x1];
  float v10 = s[y1 * 32 + x0], v11 = s[y1 * 32 + x1];
  float v = (1.f - wy) * ((1.f - wx) * v00 + wx * v01) +
            wy * ((1.f - wx) * v10 + wx * v11);
  out[idx] = v;
}

extern "C" void kernel_launch(void* const* d_in, const int* in_sizes, int n_in,
                              void* d_out, int out_size, void* d_ws, size_t ws_size,
                              hipStream_t stream) {
  const float* feats  = (const float*)d_in[0];
  const float* nfeats = (const float*)d_in[1];
  const float* mask   = (const float*)d_in[2];
  float* out = (float*)d_out;

  bf16* Abf = (bf16*)d_ws;                                     // 2*8192*768 bf16
  bf16* Bbf = Abf + (size_t)NLAY * MROWS * DD;                 // same size
  float* partials = (float*)(Bbf + (size_t)NLAY * MROWS * DD); // [2][8192][32] f32
  float* spatch   = partials + (size_t)NLAY * MROWS * NCT;     // [8][1024] f32

  normalize_kernel<<<(NLAY * MROWS) / 4, 256, 0, stream>>>(feats,  Abf, NLAY * MROWS);
  normalize_kernel<<<(NLAY * MROWS) / 4, 256, 0, stream>>>(nfeats, Bbf, NLAY * MROWS);

  dim3 g(NCT, MROWS / BM, NLAY);
  gemm_max_kernel<<<g, 512, 0, stream>>>(Abf, Bbf, partials);

  reduce_kernel<<<NN1, 1024, 0, stream>>>(partials, mask, out, spatch);

  upsample_kernel<<<(NN1 * 512 * 512) / 256, 256, 0, stream>>>(spatch, out + 8);
}